// Round 1
// baseline (131.136 us; speedup 1.0000x reference)
//
#include <hip/hip_runtime.h>
#include <hip/hip_bf16.h>

// Median blur 3x3 (kornia semantics: zero padding in (v+1)/2 space) + mask copy.
// image: [16,3,512,512] f32 -> filtered same shape; mask passthrough.
// Memory-bound: ~134 MB ideal HBM traffic -> ~21 us floor at 6.3 TB/s.

#define W 512
#define H 512
#define PLANE (W * H)          // 262144
#define NPLANES 48             // 16 * 3
#define IMG_ELEMS (PLANE * NPLANES)  // 12582912
#define MASK_ELEMS (PLANE * 16)      // 4194304

// min/max exchange
#define MM_SWAP(a, b) { float _t = fminf(a, b); b = fmaxf(a, b); a = _t; }

__device__ __forceinline__ float median9(float p0, float p1, float p2,
                                         float p3, float p4, float p5,
                                         float p6, float p7, float p8) {
    // Paeth 19-exchange median-of-9 network; result in p4.
    MM_SWAP(p1, p2); MM_SWAP(p4, p5); MM_SWAP(p7, p8);
    MM_SWAP(p0, p1); MM_SWAP(p3, p4); MM_SWAP(p6, p7);
    MM_SWAP(p1, p2); MM_SWAP(p4, p5); MM_SWAP(p7, p8);
    MM_SWAP(p0, p3); MM_SWAP(p5, p8); MM_SWAP(p4, p7);
    MM_SWAP(p3, p6); MM_SWAP(p1, p4); MM_SWAP(p2, p5);
    MM_SWAP(p4, p7); MM_SWAP(p4, p2); MM_SWAP(p6, p4);
    MM_SWAP(p4, p2);
    return p4;
}

__global__ __launch_bounds__(256) void median_blur_kernel(
        const float* __restrict__ img, float* __restrict__ out) {
    // Each thread: 4 consecutive pixels in one row.
    // idx layout: [plane (48)][y (512)][xseg (128)]
    int idx = blockIdx.x * 256 + threadIdx.x;
    int xseg = idx & 127;
    int y = (idx >> 7) & 511;
    int p = idx >> 16;           // 0..47
    int x0 = xseg << 2;          // 0,4,...,508

    const float* plane = img + (size_t)p * PLANE;

    // 3 rows x 6 columns (x0-1 .. x0+4) in transformed space t=(v+1)/2, pad=0.
    float t[3][6];
    #pragma unroll
    for (int r = 0; r < 3; ++r) {
        int yy = y + r - 1;
        if (yy < 0 || yy >= H) {
            #pragma unroll
            for (int j = 0; j < 6; ++j) t[r][j] = 0.0f;
        } else {
            const float* row = plane + yy * W;
            float4 c = *(const float4*)(row + x0);     // aligned: x0 % 4 == 0
            float lf = (x0 > 0)       ? row[x0 - 1] : -1.0f;  // -1 maps to 0
            float rt = (x0 + 4 < W)   ? row[x0 + 4] : -1.0f;
            t[r][0] = (lf  + 1.0f) * 0.5f;
            t[r][1] = (c.x + 1.0f) * 0.5f;
            t[r][2] = (c.y + 1.0f) * 0.5f;
            t[r][3] = (c.z + 1.0f) * 0.5f;
            t[r][4] = (c.w + 1.0f) * 0.5f;
            t[r][5] = (rt  + 1.0f) * 0.5f;
        }
    }

    float4 o;
    {
        float m = median9(t[0][0], t[0][1], t[0][2],
                          t[1][0], t[1][1], t[1][2],
                          t[2][0], t[2][1], t[2][2]);
        o.x = m * 2.0f - 1.0f;
    }
    {
        float m = median9(t[0][1], t[0][2], t[0][3],
                          t[1][1], t[1][2], t[1][3],
                          t[2][1], t[2][2], t[2][3]);
        o.y = m * 2.0f - 1.0f;
    }
    {
        float m = median9(t[0][2], t[0][3], t[0][4],
                          t[1][2], t[1][3], t[1][4],
                          t[2][2], t[2][3], t[2][4]);
        o.z = m * 2.0f - 1.0f;
    }
    {
        float m = median9(t[0][3], t[0][4], t[0][5],
                          t[1][3], t[1][4], t[1][5],
                          t[2][3], t[2][4], t[2][5]);
        o.w = m * 2.0f - 1.0f;
    }

    *(float4*)(out + (size_t)p * PLANE + y * W + x0) = o;
}

extern "C" void kernel_launch(void* const* d_in, const int* in_sizes, int n_in,
                              void* d_out, int out_size, void* d_ws, size_t ws_size,
                              hipStream_t stream) {
    const float* img = (const float*)d_in[0];
    const float* mask = (const float*)d_in[1];
    float* out = (float*)d_out;

    // Image: 48 planes * 512 rows * 128 segments = 3,145,728 threads / 256 = 12288 blocks
    int total_threads = NPLANES * H * (W / 4);
    int blocks = total_threads / 256;
    median_blur_kernel<<<blocks, 256, 0, stream>>>(img, out);

    // Mask passthrough: D2D copy into the second output slot.
    hipMemcpyAsync(out + IMG_ELEMS, mask, (size_t)MASK_ELEMS * sizeof(float),
                   hipMemcpyDeviceToDevice, stream);
}

// Round 2
// 127.022 us; speedup vs baseline: 1.0324x; 1.0324x over previous
//
#include <hip/hip_runtime.h>
#include <hip/hip_bf16.h>

// Median blur 3x3 (kornia semantics: zero padding in (v+1)/2 space) + fused mask copy.
// image: [16,3,512,512] f32 -> filtered same shape; mask [16,1,512,512] passthrough.
// Single dispatch: blocks [0, IMG_BLOCKS) do median, tail blocks copy mask.
// Memory-bound: ~134 MB ideal HBM traffic -> ~21 us floor at 6.3 TB/s.

#define W 512
#define H 512
#define PLANE (W * H)                 // 262144
#define NPLANES 48                    // 16 * 3
#define IMG_ELEMS (PLANE * NPLANES)   // 12582912
#define MASK_ELEMS (PLANE * 16)       // 4194304
#define IMG_BLOCKS (IMG_ELEMS / 4 / 256)   // 12288
#define MASK_BLOCKS (MASK_ELEMS / 4 / 256) // 4096

// min/max exchange (v_min_f32 / v_max_f32)
#define MM_SWAP(a, b) { float _t = fminf(a, b); b = fmaxf(a, b); a = _t; }

__device__ __forceinline__ float med3(float a, float b, float c) {
    // median of 3: max(min(a,b), min(max(a,b), c))
    return fmaxf(fminf(a, b), fminf(fmaxf(a, b), c));
}

__global__ __launch_bounds__(256) void fused_kernel(
        const float* __restrict__ img, const float* __restrict__ mask,
        float* __restrict__ out) {
    if (blockIdx.x >= IMG_BLOCKS) {
        // ---- mask copy path (block-uniform branch) ----
        int i = (blockIdx.x - IMG_BLOCKS) * 256 + threadIdx.x;  // float4 index
        const float4* src = (const float4*)mask;
        float4* dst = (float4*)(out + IMG_ELEMS);
        dst[i] = src[i];
        return;
    }

    // ---- median path: each thread does 4 consecutive pixels in one row ----
    // idx layout: [plane (48)][y (512)][xseg (128)]
    int idx = blockIdx.x * 256 + threadIdx.x;
    int xseg = idx & 127;
    int y = (idx >> 7) & 511;
    int p = idx >> 16;           // 0..47
    int x0 = xseg << 2;          // 0,4,...,508

    const float* plane = img + (size_t)p * PLANE;

    // 3 rows x 6 columns (x0-1 .. x0+4) in transformed space t=(v+1)/2, pad=0.
    float t[3][6];
    #pragma unroll
    for (int r = 0; r < 3; ++r) {
        int yy = y + r - 1;
        if (yy < 0 || yy >= H) {
            #pragma unroll
            for (int j = 0; j < 6; ++j) t[r][j] = 0.0f;
        } else {
            const float* row = plane + yy * W;
            float4 c = *(const float4*)(row + x0);     // aligned: x0 % 4 == 0
            float lf = (x0 > 0)     ? row[x0 - 1] : -1.0f;  // -1 maps to 0
            float rt = (x0 + 4 < W) ? row[x0 + 4] : -1.0f;
            t[r][0] = (lf  + 1.0f) * 0.5f;
            t[r][1] = (c.x + 1.0f) * 0.5f;
            t[r][2] = (c.y + 1.0f) * 0.5f;
            t[r][3] = (c.z + 1.0f) * 0.5f;
            t[r][4] = (c.w + 1.0f) * 0.5f;
            t[r][5] = (rt  + 1.0f) * 0.5f;
        }
    }

    // Sort each column of 3 (shared across the 4 outputs): lo/mid/hi per column.
    float lo[6], mi[6], hi[6];
    #pragma unroll
    for (int j = 0; j < 6; ++j) {
        float a = t[0][j], b = t[1][j], c = t[2][j];
        MM_SWAP(a, b); MM_SWAP(b, c); MM_SWAP(a, b);   // a<=b<=c
        lo[j] = a; mi[j] = b; hi[j] = c;
    }

    // median9 of columns {j, j+1, j+2} = med3( max(lo), med3(mi), min(hi) )
    float4 o;
    #pragma unroll
    for (int k = 0; k < 4; ++k) {
        float mx = fmaxf(fmaxf(lo[k], lo[k + 1]), lo[k + 2]);
        float md = med3(mi[k], mi[k + 1], mi[k + 2]);
        float mn = fminf(fminf(hi[k], hi[k + 1]), hi[k + 2]);
        float m = med3(mx, md, mn);
        (&o.x)[k] = m * 2.0f - 1.0f;
    }

    *(float4*)(out + (size_t)p * PLANE + y * W + x0) = o;
}

extern "C" void kernel_launch(void* const* d_in, const int* in_sizes, int n_in,
                              void* d_out, int out_size, void* d_ws, size_t ws_size,
                              hipStream_t stream) {
    const float* img  = (const float*)d_in[0];
    const float* mask = (const float*)d_in[1];
    float* out = (float*)d_out;

    fused_kernel<<<IMG_BLOCKS + MASK_BLOCKS, 256, 0, stream>>>(img, mask, out);
}

// Round 3
// 116.765 us; speedup vs baseline: 1.1231x; 1.0878x over previous
//
#include <hip/hip_runtime.h>
#include <hip/hip_bf16.h>

// Median blur 3x3 (kornia semantics) + fused mask copy.
// Algebraic simplification: median commutes with monotone affine maps, so
//   2*median((v+1)/2) - 1 == median(v)   with pad sentinel -1.0
// (reference zero-pads in (v+1)/2 space; -1 maps to 0 there). No transforms.
//
// Each median thread: 4x4 output pixels (4 rows x float4). Loads 6 rows x 6
// cols (18 vmem insts, all independent -> deep MLP), reuses horizontal
// triple-sorts across the 3 output rows touching each loaded row.

#define W 512
#define H 512
#define PLANE (W * H)                 // 262144
#define NPLANES 48                    // 16 * 3
#define IMG_ELEMS (PLANE * NPLANES)   // 12582912
#define MASK_ELEMS (PLANE * 16)       // 4194304
#define MED_BLOCKS (NPLANES * (H / 4) * (W / 4) / 256)  // 3072
#define MASK_F4 (MASK_ELEMS / 4)      // 1048576
#define MASK_BLOCKS (MASK_F4 / 4 / 256)                 // 1024

#define MM_SWAP(a, b) { float _t = fminf(a, b); b = fmaxf(a, b); a = _t; }

__device__ __forceinline__ float med3(float a, float b, float c) {
    return fmaxf(fminf(a, b), fminf(fmaxf(a, b), c));
}

__global__ __launch_bounds__(256) void fused_kernel(
        const float* __restrict__ img, const float* __restrict__ mask,
        float* __restrict__ out) {
    if (blockIdx.x >= MED_BLOCKS) {
        // ---- mask copy: 4 float4 per thread, chunk-strided (coalesced) ----
        int i = (blockIdx.x - MED_BLOCKS) * 256 + threadIdx.x;
        const float4* src = (const float4*)mask;
        float4* dst = (float4*)(out + IMG_ELEMS);
        #pragma unroll
        for (int k = 0; k < 4; ++k) {
            int j = i + k * (MASK_F4 / 4);
            dst[j] = src[j];
        }
        return;
    }

    // ---- median path: [plane 48][rowblk 128][xseg 128] ----
    int idx = blockIdx.x * 256 + threadIdx.x;
    int xseg = idx & 127;
    int rb = (idx >> 7) & 127;
    int p = idx >> 14;              // 0..47
    int x0 = xseg << 2;             // 0..508
    int y0 = rb << 2;               // 0..508

    const float* plane = img + (size_t)p * PLANE;

    // Load 6 rows (y0-1 .. y0+4) x 6 cols (x0-1 .. x0+4); pad = -1.0f.
    float t[6][6];
    #pragma unroll
    for (int r = 0; r < 6; ++r) {
        int yy = y0 + r - 1;
        if (yy >= 0 && yy < H) {    // wave-uniform branch (rb uniform in wave)
            const float* row = plane + yy * W;
            float4 c = *(const float4*)(row + x0);   // aligned
            t[r][1] = c.x; t[r][2] = c.y; t[r][3] = c.z; t[r][4] = c.w;
            t[r][0] = (x0 > 0)     ? row[x0 - 1] : -1.0f;
            t[r][5] = (x0 + 4 < W) ? row[x0 + 4] : -1.0f;
        } else {
            #pragma unroll
            for (int j = 0; j < 6; ++j) t[r][j] = -1.0f;
        }
    }

    // Horizontal triple-sorts, once per loaded row, reused by up to 3 output
    // rows: rl/rm/rh[r][k] = sorted {t[r][k], t[r][k+1], t[r][k+2]}.
    float rl[6][4], rm[6][4], rh[6][4];
    #pragma unroll
    for (int r = 0; r < 6; ++r) {
        #pragma unroll
        for (int k = 0; k < 4; ++k) {
            float a = t[r][k], b = t[r][k + 1], c = t[r][k + 2];
            MM_SWAP(a, b); MM_SWAP(b, c); MM_SWAP(a, b);   // a<=b<=c
            rl[r][k] = a; rm[r][k] = b; rh[r][k] = c;
        }
    }

    // median9 = med3( max3(row-los), med3(row-mids), min3(row-his) )
    float* outp = out + (size_t)p * PLANE + y0 * W + x0;
    #pragma unroll
    for (int oy = 0; oy < 4; ++oy) {
        float4 o;
        #pragma unroll
        for (int k = 0; k < 4; ++k) {
            float mx = fmaxf(fmaxf(rl[oy][k], rl[oy + 1][k]), rl[oy + 2][k]);
            float md = med3(rm[oy][k], rm[oy + 1][k], rm[oy + 2][k]);
            float mn = fminf(fminf(rh[oy][k], rh[oy + 1][k]), rh[oy + 2][k]);
            (&o.x)[k] = med3(mx, md, mn);
        }
        *(float4*)(outp + oy * W) = o;
    }
}

extern "C" void kernel_launch(void* const* d_in, const int* in_sizes, int n_in,
                              void* d_out, int out_size, void* d_ws, size_t ws_size,
                              hipStream_t stream) {
    const float* img  = (const float*)d_in[0];
    const float* mask = (const float*)d_in[1];
    float* out = (float*)d_out;

    fused_kernel<<<MED_BLOCKS + MASK_BLOCKS, 256, 0, stream>>>(img, mask, out);
}